// Round 1
// baseline (77.700 us; speedup 1.0000x reference)
//
#include <hip/hip_runtime.h>
#include <math.h>

// Problem constants (from reference)
#define NPTS   30929          // total points across 5 levels
#define BATCH  4
#define NGT    64             // M gt boxes per batch
#define BN     (BATCH * NPTS) // 123716 rows per output tensor
#define INF_F  1e8f

// Level tables: offsets {0,23200,29000,30450,30825,30929}
// widths {200,100,50,25,13}, strides {8,16,32,64,128}
// regress ranges {(-1,48),(48,96),(96,192),(192,384),(384,1e8)}

__global__ __launch_bounds__(256)
void fcos3d_target_kernel(const float* __restrict__ gt_bboxes,    // (B,M,4)
                          const float* __restrict__ gt_bboxes_3d, // (B,M,9)
                          const int*   __restrict__ gt_labels_3d, // (B,M)
                          const float* __restrict__ centers2d,    // (B,M,2)
                          const float* __restrict__ depths,       // (B,M)
                          const int*   __restrict__ attr_labels,  // (B,M)
                          float* __restrict__ out)
{
#pragma clang fp contract(off)
    const int b = blockIdx.y;
    const int p = blockIdx.x * blockDim.x + threadIdx.x;

    // Stage this batch's GT hot-loop data in LDS (64 boxes * 6 floats)
    __shared__ float s_cx[NGT], s_cy[NGT], s_x0[NGT], s_y0[NGT], s_x1[NGT], s_y1[NGT];
    if (threadIdx.x < NGT) {
        const int m  = threadIdx.x;
        const int gi = b * NGT + m;
        s_cx[m] = centers2d[gi * 2 + 0];
        s_cy[m] = centers2d[gi * 2 + 1];
        s_x0[m] = gt_bboxes[gi * 4 + 0];
        s_y0[m] = gt_bboxes[gi * 4 + 1];
        s_x1[m] = gt_bboxes[gi * 4 + 2];
        s_y1[m] = gt_bboxes[gi * 4 + 3];
    }
    __syncthreads();
    if (p >= NPTS) return;

    // Level lookup
    int lvl;
    if      (p < 23200) lvl = 0;
    else if (p < 29000) lvl = 1;
    else if (p < 30450) lvl = 2;
    else if (p < 30825) lvl = 3;
    else                lvl = 4;

    const int   off_tab[6] = {0, 23200, 29000, 30450, 30825, 30929};
    const int   w_tab[5]   = {200, 100, 50, 25, 13};
    const float s_tab[5]   = {8.f, 16.f, 32.f, 64.f, 128.f};
    const float rr0_tab[5] = {-1.f, 48.f, 96.f, 192.f, 384.f};
    const float rr1_tab[5] = {48.f, 96.f, 192.f, 384.f, 1e8f};

    const int   off    = off_tab[lvl];
    const int   pl     = p - off;
    const int   w      = w_tab[lvl];
    const float stride = s_tab[lvl];
    const int   row    = pl / w;
    const int   col    = pl - row * w;
    // xs = col*s + s//2 ; strides are even so s//2 == 0.5*s exactly
    const float x = (float)col * stride + 0.5f * stride;
    const float y = (float)row * stride + 0.5f * stride;
    const float r = stride * 1.5f;         // RADIUS = 1.5
    const float rr0 = rr0_tab[lvl], rr1 = rr1_tab[lvl];

    // Argmin over masked distances (first-occurrence semantics: strict <)
    float best = INF_F;
    int   ind  = 0;
    #pragma unroll 4
    for (int m = 0; m < NGT; ++m) {
        const float cx = s_cx[m], cy = s_cy[m];
        const float dx = x - cx;
        const float dy = y - cy;
        const float left   = x - s_x0[m];
        const float top    = y - s_y0[m];
        const float right  = s_x1[m] - x;
        const float bottom = s_y1[m] - y;
        const float mrd = fmaxf(fmaxf(left, top), fmaxf(right, bottom));
        const float cb1 = fminf(x - (cx - r), (cx + r) - x);
        const float cb2 = fminf(y - (cy - r), (cy + r) - y);
        const float cbm = fminf(cb1, cb2);
        const bool cond = (cbm > 0.f) && (mrd >= rr0) && (mrd <= rr1);
        const float d = cond ? sqrtf(dx * dx + dy * dy) : INF_F;
        if (d < best) { best = d; ind = m; }
    }
    const bool bg = (best >= INF_F);
    const int  gi = b * NGT + ind;

    const int label = bg ? 10 : gt_labels_3d[gi];  // NUM_CLASSES = 10
    const int attr  = bg ? 9  : attr_labels[gi];   // NUM_ATTRS = 9

    // Gather targets from the selected box (even for background, like the ref)
    const float cx = s_cx[ind], cy = s_cy[ind];
    const float dx = x - cx;
    const float dy = y - cy;
    const float depth = depths[gi];
    const float g0 = gt_bboxes_3d[gi * 9 + 0];
    const float g2 = gt_bboxes_3d[gi * 9 + 2];
    const float g6 = gt_bboxes_3d[gi * 9 + 6];
    const float yaw = -atan2f(g0, g2) + g6;

    // centerness: exp(-ALPHA * sqrt(dx^2+dy^2) / (1.414 * stride * RADIUS))
    const float rel  = sqrtf(dx * dx + dy * dy) / (1.414f * stride * 1.5f);
    const float cent = expf(-2.5f * rel);

    // Output index: levels concatenated, batch-major within level
    const int n_lvl = off_tab[lvl + 1] - off;
    const int gidx  = BATCH * off + b * n_lvl + pl;

    // Output layout: [labels(BN)] [bt3d(BN,9)] [centerness(BN)] [attr(BN)]
    out[gidx] = (float)label;
    float* bo = out + BN + (size_t)gidx * 9;
    bo[0] = dx / stride;
    bo[1] = dy / stride;
    bo[2] = depth;
    bo[3] = gt_bboxes_3d[gi * 9 + 3];
    bo[4] = gt_bboxes_3d[gi * 9 + 4];
    bo[5] = gt_bboxes_3d[gi * 9 + 5];
    bo[6] = yaw;
    bo[7] = gt_bboxes_3d[gi * 9 + 7];
    bo[8] = gt_bboxes_3d[gi * 9 + 8];
    out[(size_t)BN * 10 + gidx] = cent;
    out[(size_t)BN * 11 + gidx] = (float)attr;
}

extern "C" void kernel_launch(void* const* d_in, const int* in_sizes, int n_in,
                              void* d_out, int out_size, void* d_ws, size_t ws_size,
                              hipStream_t stream) {
    // setup_inputs() order:
    // 0: gt_bboxes (B,M,4) f32      1: gt_labels (B,M) i32 [unused]
    // 2: gt_bboxes_3d (B,M,9) f32   3: gt_labels_3d (B,M) i32
    // 4: centers2d (B,M,2) f32      5: depths (B,M) f32
    // 6: attr_labels (B,M) i32
    const float* gt_bboxes    = (const float*)d_in[0];
    const float* gt_bboxes_3d = (const float*)d_in[2];
    const int*   gt_labels_3d = (const int*)d_in[3];
    const float* centers2d    = (const float*)d_in[4];
    const float* depths       = (const float*)d_in[5];
    const int*   attr_labels  = (const int*)d_in[6];
    float* out = (float*)d_out;

    dim3 grid((NPTS + 255) / 256, BATCH);
    fcos3d_target_kernel<<<grid, 256, 0, stream>>>(
        gt_bboxes, gt_bboxes_3d, gt_labels_3d, centers2d, depths, attr_labels, out);
}